// Round 2
// baseline (446.278 us; speedup 1.0000x reference)
//
#include <hip/hip_runtime.h>

#define LAMBDA_INIT 0.78360576653162448f

typedef __attribute__((ext_vector_type(8))) short short8;
typedef __attribute__((ext_vector_type(4))) float f32x4;

__device__ __forceinline__ unsigned short f2bf(float f) {
  unsigned int u; __builtin_memcpy(&u, &f, 4);
  u += 0x7fffu + ((u >> 16) & 1u);
  return (unsigned short)(u >> 16);
}
__device__ __forceinline__ short8 cvt8(float4 a, float4 b) {
  short8 s;
  s[0] = (short)f2bf(a.x); s[1] = (short)f2bf(a.y);
  s[2] = (short)f2bf(a.z); s[3] = (short)f2bf(a.w);
  s[4] = (short)f2bf(b.x); s[5] = (short)f2bf(b.y);
  s[6] = (short)f2bf(b.z); s[7] = (short)f2bf(b.w);
  return s;
}

// Async global->LDS, 16 B per lane, wave-uniform LDS base + lane*16.
#define GLOAD_LDS16(g, l)                                                     \
  __builtin_amdgcn_global_load_lds(                                           \
      (const __attribute__((address_space(1))) void*)(g),                     \
      (__attribute__((address_space(3))) void*)(l), 16, 0, 0)

// f32 -> bf16 bulk convert, 8 elems/thread (x only; fallback path).
__global__ void conv_bf16(const float* __restrict__ in,
                          unsigned short* __restrict__ outp, int n8) {
  const int i = blockIdx.x * 256 + threadIdx.x;
  if (i >= n8) return;
  const float4 a = *(const float4*)(in + (size_t)i * 8);
  const float4 b = *(const float4*)(in + (size_t)i * 8 + 4);
  *(short8*)(outp + (size_t)i * 8) = cvt8(a, b);
}

// Fused f32->bf16 convert of x + all four weights into ws (fast path).
__global__ void conv_all(const float* __restrict__ x, const float* __restrict__ wq,
                         const float* __restrict__ wk, const float* __restrict__ wv,
                         const float* __restrict__ wo, unsigned short* __restrict__ ws) {
  const int i = blockIdx.x * 256 + threadIdx.x;  // unit of 8 elems
  const float* src; size_t so; unsigned short* dst;
  if (i < 1048576)      { src = x;  so = i;           dst = ws; }
  else if (i < 1572864) { src = wq; so = i - 1048576; dst = ws + 8388608; }
  else if (i < 1835008) { src = wk; so = i - 1572864; dst = ws + 12582912; }
  else if (i < 2097152) { src = wv; so = i - 1835008; dst = ws + 14680064; }
  else                  { src = wo; so = i - 2097152; dst = ws + 16777216; }
  const float4 a = *(const float4*)(src + so * 8);
  const float4 b = *(const float4*)(src + so * 8 + 4);
  *(short8*)(dst + so * 8) = cvt8(a, b);
}

// ---------- Fast-path GEMMs: both operands bf16, staged via global_load_lds.

__global__ __launch_bounds__(256, 2)
void qkv_bb(const unsigned short* __restrict__ xb,
            const unsigned short* __restrict__ Wqb, const unsigned short* __restrict__ Wkb,
            const unsigned short* __restrict__ Wvb, const float* __restrict__ cosb,
            const float* __restrict__ sinb,
            unsigned short* __restrict__ Qb, unsigned short* __restrict__ Kb,
            unsigned short* __restrict__ Vtb) {
  __shared__ __align__(16) unsigned short As[128 * 64];
  __shared__ __align__(16) unsigned short Bs[128 * 64];
  const int t = threadIdx.x;
  const int wave = t >> 6, lane = t & 63;
  const int l15 = lane & 15, l4 = lane >> 4;
  const int wm = (wave >> 1) * 64, wn = (wave & 1) * 64;
  const int m0 = blockIdx.y * 128, n0 = blockIdx.x * 128;
  const int crow = t >> 3, ccol = (t & 7) * 8;
  const unsigned short* Ag = xb + (size_t)m0 * 2048;

  const unsigned short* Bgh; int ntype;
  if (n0 < 2048)      { Bgh = Wqb + (size_t)n0 * 2048;          ntype = 0; }
  else if (n0 < 3072) { Bgh = Wkb + (size_t)(n0 - 2048) * 2048; ntype = 1; }
  else                { Bgh = Wvb + (size_t)(n0 - 3072) * 2048; ntype = 2; }

  const f32x4 fzero = {0.f, 0.f, 0.f, 0.f};
  f32x4 acc[4][4];
#pragma unroll
  for (int i = 0; i < 4; i++)
#pragma unroll
    for (int j = 0; j < 4; j++) acc[i][j] = fzero;

  for (int kt = 0; kt < 32; ++kt) {
    const int k0 = kt << 6;
    __syncthreads();
#pragma unroll
    for (int j = 0; j < 4; j++) {
      GLOAD_LDS16(Ag + (size_t)(j * 32 + crow) * 2048 + k0 + ccol,
                  &As[j * 2048 + wave * 512]);
      GLOAD_LDS16(Bgh + (size_t)(j * 32 + crow) * 2048 + k0 + ccol,
                  &Bs[j * 2048 + wave * 512]);
    }
    __syncthreads();
#pragma unroll
    for (int ks = 0; ks < 2; ++ks) {
      short8 af[4], bfr[4];
#pragma unroll
      for (int mi = 0; mi < 4; mi++)
        af[mi] = *(const short8*)(&As[(wm + mi * 16 + l15) * 64 + ks * 32 + l4 * 8]);
#pragma unroll
      for (int ni = 0; ni < 4; ni++)
        bfr[ni] = *(const short8*)(&Bs[(wn + ni * 16 + l15) * 64 + ks * 32 + l4 * 8]);
#pragma unroll
      for (int mi = 0; mi < 4; mi++)
#pragma unroll
        for (int ni = 0; ni < 4; ni++)
          acc[mi][ni] = __builtin_amdgcn_mfma_f32_16x16x32_bf16(af[mi], bfr[ni], acc[mi][ni], 0, 0, 0);
    }
  }
#pragma unroll
  for (int mi = 0; mi < 4; mi++)
#pragma unroll
    for (int ni = 0; ni < 4; ni++)
#pragma unroll
      for (int r = 0; r < 4; r++) {
        const int m = m0 + wm + mi * 16 + l4 * 4 + r;
        const int n = n0 + wn + ni * 16 + l15;
        float fv = acc[mi][ni][r];
        if (ntype < 2) {
          const int s = m & 2047;
          const int j = (n & 63) >> 1;
          const float c = cosb[s * 32 + j];
          const float sn = sinb[s * 32 + j];
          const float p = __shfl_xor(fv, 1);
          fv = (n & 1) ? (p * sn + fv * c) : (fv * c - p * sn);
        }
        if (ntype == 0)
          Qb[(size_t)m * 2048 + n] = f2bf(fv);
        else if (ntype == 1)
          Kb[(size_t)m * 1024 + (n - 2048)] = f2bf(fv);
        else
          Vtb[((size_t)((m >> 11) * 1024 + (n - 3072))) * 2048 + (m & 2047)] = f2bf(fv);
      }
}

// O-projection, both operands bf16, C f32.
__global__ __launch_bounds__(256, 2)
void o_bb(const unsigned short* __restrict__ Ab, const unsigned short* __restrict__ Wob,
          float* __restrict__ C) {
  __shared__ __align__(16) unsigned short As[128 * 64];
  __shared__ __align__(16) unsigned short Bs[128 * 64];
  const int t = threadIdx.x;
  const int wave = t >> 6, lane = t & 63;
  const int l15 = lane & 15, l4 = lane >> 4;
  const int wm = (wave >> 1) * 64, wn = (wave & 1) * 64;
  const int m0 = blockIdx.y * 128, n0 = blockIdx.x * 128;
  const int crow = t >> 3, ccol = (t & 7) * 8;
  const unsigned short* Ag = Ab + (size_t)m0 * 2048;
  const unsigned short* Bgh = Wob + (size_t)n0 * 2048;

  const f32x4 fzero = {0.f, 0.f, 0.f, 0.f};
  f32x4 acc[4][4];
#pragma unroll
  for (int i = 0; i < 4; i++)
#pragma unroll
    for (int j = 0; j < 4; j++) acc[i][j] = fzero;

  for (int kt = 0; kt < 32; ++kt) {
    const int k0 = kt << 6;
    __syncthreads();
#pragma unroll
    for (int j = 0; j < 4; j++) {
      GLOAD_LDS16(Ag + (size_t)(j * 32 + crow) * 2048 + k0 + ccol,
                  &As[j * 2048 + wave * 512]);
      GLOAD_LDS16(Bgh + (size_t)(j * 32 + crow) * 2048 + k0 + ccol,
                  &Bs[j * 2048 + wave * 512]);
    }
    __syncthreads();
#pragma unroll
    for (int ks = 0; ks < 2; ++ks) {
      short8 af[4], bfr[4];
#pragma unroll
      for (int mi = 0; mi < 4; mi++)
        af[mi] = *(const short8*)(&As[(wm + mi * 16 + l15) * 64 + ks * 32 + l4 * 8]);
#pragma unroll
      for (int ni = 0; ni < 4; ni++)
        bfr[ni] = *(const short8*)(&Bs[(wn + ni * 16 + l15) * 64 + ks * 32 + l4 * 8]);
#pragma unroll
      for (int mi = 0; mi < 4; mi++)
#pragma unroll
        for (int ni = 0; ni < 4; ni++)
          acc[mi][ni] = __builtin_amdgcn_mfma_f32_16x16x32_bf16(af[mi], bfr[ni], acc[mi][ni], 0, 0, 0);
    }
  }
#pragma unroll
  for (int mi = 0; mi < 4; mi++)
#pragma unroll
    for (int ni = 0; ni < 4; ni++)
#pragma unroll
      for (int r = 0; r < 4; r++) {
        const int m = m0 + wm + mi * 16 + l4 * 4 + r;
        const int n = n0 + wn + ni * 16 + l15;
        C[(size_t)m * 2048 + n] = acc[mi][ni][r];
      }
}

// ---------- Fallback GEMMs (round-6 proven): B from f32 weights.

__global__ __launch_bounds__(256, 2)
void qkv_gemm_f32(const unsigned short* __restrict__ xb,
                  const float* __restrict__ Wq, const float* __restrict__ Wk,
                  const float* __restrict__ Wv, const float* __restrict__ cosb,
                  const float* __restrict__ sinb,
                  unsigned short* __restrict__ Qb, unsigned short* __restrict__ Kb,
                  unsigned short* __restrict__ Vtb) {
  __shared__ __align__(16) unsigned short As[128 * 64];
  __shared__ __align__(16) unsigned short Bs[128 * 72];
  const int t = threadIdx.x;
  const int wave = t >> 6, lane = t & 63;
  const int l15 = lane & 15, l4 = lane >> 4;
  const int wm = (wave >> 1) * 64, wn = (wave & 1) * 64;
  const int m0 = blockIdx.y * 128, n0 = blockIdx.x * 128;
  const int crow = t >> 3, ccol = (t & 7) * 8;
  const unsigned short* Ag = xb + (size_t)m0 * 2048;

  const float* Bg; int ntype;
  if (n0 < 2048)      { Bg = Wq + (size_t)n0 * 2048;          ntype = 0; }
  else if (n0 < 3072) { Bg = Wk + (size_t)(n0 - 2048) * 2048; ntype = 1; }
  else                { Bg = Wv + (size_t)(n0 - 3072) * 2048; ntype = 2; }

  const f32x4 fzero = {0.f, 0.f, 0.f, 0.f};
  f32x4 acc[4][4];
#pragma unroll
  for (int i = 0; i < 4; i++)
#pragma unroll
    for (int j = 0; j < 4; j++) acc[i][j] = fzero;

  float4 rbf[4][2];
#pragma unroll
  for (int i = 0; i < 4; i++) {
    rbf[i][0] = *(const float4*)(Bg + (size_t)(crow + 32 * i) * 2048 + ccol);
    rbf[i][1] = *(const float4*)(Bg + (size_t)(crow + 32 * i) * 2048 + ccol + 4);
  }
  for (int kt = 0; kt < 32; ++kt) {
    const int k0 = kt << 6;
    __syncthreads();
#pragma unroll
    for (int j = 0; j < 4; j++)
      GLOAD_LDS16(Ag + (size_t)(j * 32 + crow) * 2048 + k0 + ccol,
                  &As[j * 2048 + wave * 512]);
#pragma unroll
    for (int i = 0; i < 4; i++)
      *(short8*)(&Bs[(crow + 32 * i) * 72 + ccol]) = cvt8(rbf[i][0], rbf[i][1]);
    __syncthreads();
    if (kt + 1 < 32) {
      const int kn = k0 + 64;
#pragma unroll
      for (int i = 0; i < 4; i++) {
        rbf[i][0] = *(const float4*)(Bg + (size_t)(crow + 32 * i) * 2048 + kn + ccol);
        rbf[i][1] = *(const float4*)(Bg + (size_t)(crow + 32 * i) * 2048 + kn + ccol + 4);
      }
    }
#pragma unroll
    for (int ks = 0; ks < 2; ++ks) {
      short8 af[4], bfr[4];
#pragma unroll
      for (int mi = 0; mi < 4; mi++)
        af[mi] = *(const short8*)(&As[(wm + mi * 16 + l15) * 64 + ks * 32 + l4 * 8]);
#pragma unroll
      for (int ni = 0; ni < 4; ni++)
        bfr[ni] = *(const short8*)(&Bs[(wn + ni * 16 + l15) * 72 + ks * 32 + l4 * 8]);
#pragma unroll
      for (int mi = 0; mi < 4; mi++)
#pragma unroll
        for (int ni = 0; ni < 4; ni++)
          acc[mi][ni] = __builtin_amdgcn_mfma_f32_16x16x32_bf16(af[mi], bfr[ni], acc[mi][ni], 0, 0, 0);
    }
  }
#pragma unroll
  for (int mi = 0; mi < 4; mi++)
#pragma unroll
    for (int ni = 0; ni < 4; ni++)
#pragma unroll
      for (int r = 0; r < 4; r++) {
        const int m = m0 + wm + mi * 16 + l4 * 4 + r;
        const int n = n0 + wn + ni * 16 + l15;
        float fv = acc[mi][ni][r];
        if (ntype < 2) {
          const int s = m & 2047;
          const int j = (n & 63) >> 1;
          const float c = cosb[s * 32 + j];
          const float sn = sinb[s * 32 + j];
          const float p = __shfl_xor(fv, 1);
          fv = (n & 1) ? (p * sn + fv * c) : (fv * c - p * sn);
        }
        if (ntype == 0)
          Qb[(size_t)m * 2048 + n] = f2bf(fv);
        else if (ntype == 1)
          Kb[(size_t)m * 1024 + (n - 2048)] = f2bf(fv);
        else
          Vtb[((size_t)((m >> 11) * 1024 + (n - 3072))) * 2048 + (m & 2047)] = f2bf(fv);
      }
}

__global__ __launch_bounds__(256, 2)
void o_gemm_f32(const unsigned short* __restrict__ Ab, const float* __restrict__ Wo,
                float* __restrict__ C) {
  __shared__ __align__(16) unsigned short As[128 * 64];
  __shared__ __align__(16) unsigned short Bs[128 * 72];
  const int t = threadIdx.x;
  const int wave = t >> 6, lane = t & 63;
  const int l15 = lane & 15, l4 = lane >> 4;
  const int wm = (wave >> 1) * 64, wn = (wave & 1) * 64;
  const int m0 = blockIdx.y * 128, n0 = blockIdx.x * 128;
  const int crow = t >> 3, ccol = (t & 7) * 8;
  const unsigned short* Ag = Ab + (size_t)m0 * 2048;
  const float* Bg = Wo + (size_t)n0 * 2048;

  const f32x4 fzero = {0.f, 0.f, 0.f, 0.f};
  f32x4 acc[4][4];
#pragma unroll
  for (int i = 0; i < 4; i++)
#pragma unroll
    for (int j = 0; j < 4; j++) acc[i][j] = fzero;

  float4 rbf[4][2];
#pragma unroll
  for (int i = 0; i < 4; i++) {
    rbf[i][0] = *(const float4*)(Bg + (size_t)(crow + 32 * i) * 2048 + ccol);
    rbf[i][1] = *(const float4*)(Bg + (size_t)(crow + 32 * i) * 2048 + ccol + 4);
  }
  for (int kt = 0; kt < 32; ++kt) {
    const int k0 = kt << 6;
    __syncthreads();
#pragma unroll
    for (int j = 0; j < 4; j++)
      GLOAD_LDS16(Ag + (size_t)(j * 32 + crow) * 2048 + k0 + ccol,
                  &As[j * 2048 + wave * 512]);
#pragma unroll
    for (int i = 0; i < 4; i++)
      *(short8*)(&Bs[(crow + 32 * i) * 72 + ccol]) = cvt8(rbf[i][0], rbf[i][1]);
    __syncthreads();
    if (kt + 1 < 32) {
      const int kn = k0 + 64;
#pragma unroll
      for (int i = 0; i < 4; i++) {
        rbf[i][0] = *(const float4*)(Bg + (size_t)(crow + 32 * i) * 2048 + kn + ccol);
        rbf[i][1] = *(const float4*)(Bg + (size_t)(crow + 32 * i) * 2048 + kn + ccol + 4);
      }
    }
#pragma unroll
    for (int ks = 0; ks < 2; ++ks) {
      short8 af[4], bfr[4];
#pragma unroll
      for (int mi = 0; mi < 4; mi++)
        af[mi] = *(const short8*)(&As[(wm + mi * 16 + l15) * 64 + ks * 32 + l4 * 8]);
#pragma unroll
      for (int ni = 0; ni < 4; ni++)
        bfr[ni] = *(const short8*)(&Bs[(wn + ni * 16 + l15) * 72 + ks * 32 + l4 * 8]);
#pragma unroll
      for (int mi = 0; mi < 4; mi++)
#pragma unroll
        for (int ni = 0; ni < 4; ni++)
          acc[mi][ni] = __builtin_amdgcn_mfma_f32_16x16x32_bf16(af[mi], bfr[ni], acc[mi][ni], 0, 0, 0);
    }
  }
#pragma unroll
  for (int mi = 0; mi < 4; mi++)
#pragma unroll
    for (int ni = 0; ni < 4; ni++)
#pragma unroll
      for (int r = 0; r < 4; r++) {
        const int m = m0 + wm + mi * 16 + l4 * 4 + r;
        const int n = n0 + wn + ni * 16 + l15;
        C[(size_t)m * 2048 + n] = acc[mi][ni][r];
      }
}

// ---------- Fused differential flash attention, restructured:
//  - 128-row q-tile per block, 4 waves x 32 q-rows (2 strips of 16).
//    LDS K/V read bytes per q-row drop 2.25 -> 1.25 reads/row; barriers/work halved.
//  - grid (16,32); qi = b ? 15-pi : pi pairs heavy+light blocks on a CU.
//  - K/V staged via global_load_lds with XOR-pre-swizzled SOURCE cols
//    (linear LDS dest); all LDS tiles stride 64 shorts + (row&7)<<3 XOR swizzle
//    => conflict-free fragment reads (8 lanes / 16B slot).
//  - Q fragments loaded global->reg once per block (no LDS staging).
//  - Single-c P buffer: write P, read own-wave pf (wave-local rows, no barrier).
//    LDS total 48 KB -> 2 blocks/CU guaranteed.
__global__ __launch_bounds__(256, 2)
void attn_kernel(const unsigned short* __restrict__ Q,
                 const unsigned short* __restrict__ Kb,
                 const unsigned short* __restrict__ Vt,
                 unsigned short* __restrict__ Ab,
                 const float* __restrict__ lq1,
                 const float* __restrict__ lk1,
                 const float* __restrict__ lq2,
                 const float* __restrict__ lk2,
                 const float* __restrict__ wsub) {
  const int pi = blockIdx.x;                 // 0..15
  const int bh = blockIdx.y;                 // b*16 + h
  const int b = bh >> 4, h = bh & 15, hk = h >> 1;
  const int qi = b ? (15 - pi) : pi;         // complementary pairing across co-resident blocks
  const int q0 = qi * 128;
  const int nkt = 2 * qi + 2;

  __shared__ __align__(16) unsigned short Ks[2][64 * 64];
  __shared__ __align__(16) unsigned short Vs[128 * 64];
  __shared__ __align__(16) unsigned short Ps[128 * 64];

  const int t = threadIdx.x;
  const int wave = t >> 6, lane = t & 63;
  const int l15 = lane & 15, l4 = lane >> 4;
  const int crow = t >> 3, ccol = (t & 7) * 8;
  const int swc = ccol ^ ((crow & 7) << 3);  // pre-swizzled source col for staging

  float s1 = 0.f, s2 = 0.f;
  for (int i = 0; i < 64; i++) {
    s1 += lq1[i] * lk1[i];
    s2 += lq2[i] * lk2[i];
  }
  const float lam = __expf(s1) - __expf(s2) + LAMBDA_INIT;

  // ones B-fragment: B[k][n] = (n==0) ? 1 : 0  (bf16 1.0 = 0x3F80)
  short8 onesf;
#pragma unroll
  for (int j = 0; j < 8; j++) onesf[j] = (l15 == 0) ? (short)0x3F80 : (short)0;

  // Q fragments, direct global->reg (once per block; rows are wave-exclusive).
  const int wrow = q0 + wave * 32;
  short8 qf[2][2][2];  // [strip][c][ks]
#pragma unroll
  for (int s = 0; s < 2; s++)
#pragma unroll
    for (int c = 0; c < 2; c++)
#pragma unroll
      for (int ks = 0; ks < 2; ks++)
        qf[s][c][ks] = *(const short8*)(Q + ((size_t)(b * 2048 + wrow + s * 16 + l15)) * 2048
                                          + (2 * h + c) * 64 + ks * 32 + l4 * 8);

  const f32x4 fzero = {0.f, 0.f, 0.f, 0.f};
  f32x4 accO[2][2][8];  // [strip][c][nt]
  f32x4 accL[2][2];
#pragma unroll
  for (int s = 0; s < 2; s++)
#pragma unroll
    for (int c = 0; c < 2; c++) {
      accL[s][c] = fzero;
#pragma unroll
      for (int nt = 0; nt < 8; nt++) accO[s][c][nt] = fzero;
    }

  const unsigned short* Kgb = Kb + ((size_t)(b * 2048)) * 1024 + 2 * hk * 64;
  const unsigned short* Vgb = Vt + ((size_t)((b * 8 + hk) * 128)) * 2048;

  for (int kt = 0; kt < nkt; ++kt) {
    const int k0 = kt << 6;
    __syncthreads();  // all waves done reading previous Ks/Vs
    // Async staging with pre-swizzled global source columns, linear LDS dest.
#pragma unroll
    for (int c = 0; c < 2; c++)
#pragma unroll
      for (int i = 0; i < 2; i++)
        GLOAD_LDS16(Kgb + (size_t)(k0 + i * 32 + crow) * 1024 + c * 64 + swc,
                    &Ks[c][i * 2048 + wave * 512]);
#pragma unroll
    for (int i = 0; i < 4; i++)
      GLOAD_LDS16(Vgb + (size_t)(i * 32 + crow) * 2048 + k0 + swc,
                  &Vs[i * 2048 + wave * 512]);
    __syncthreads();  // compiler drains vmcnt before s_barrier

    // ---- QK^T -> softmax numerator -> P (LDS, wave-local rows) -> pf frags
    short8 pf[2][2][2];  // [strip][c][ks]
#pragma unroll
    for (int c = 0; c < 2; c++) {
#pragma unroll
      for (int ct = 0; ct < 4; ct++) {
        const int kr = ct * 16 + l15;
        const int ksw = (kr & 7) << 3;
        const short8 kb0 = *(const short8*)(&Ks[c][kr * 64 + ((l4 * 8) ^ ksw)]);
        const short8 kb1 = *(const short8*)(&Ks[c][kr * 64 + ((32 + l4 * 8) ^ ksw)]);
#pragma unroll
        for (int s = 0; s < 2; s++) {
          f32x4 z = fzero;
          z = __builtin_amdgcn_mfma_f32_16x16x32_bf16(qf[s][c][0], kb0, z, 0, 0, 0);
          z = __builtin_amdgcn_mfma_f32_16x16x32_bf16(qf[s][c][1], kb1, z, 0, 0, 0);
          const int rbase = wave * 32 + s * 16 + l4 * 4;
          const bool needm = (k0 + 63) > (q0 + wave * 32 + s * 16);  // wave-uniform
#pragma unroll
          for (int r = 0; r < 4; r++) {
            // exp(0.125*z - 16) as exp2(z*0.125*log2e - 16*log2e)
            float e = exp2f(fmaf(z[r], 0.18033688011112042f, -23.083120654223414f));
            if (needm && (k0 + ct * 16 + l15) > (q0 + rbase + r)) e = 0.f;
            const int prow = rbase + r;
            Ps[prow * 64 + ((ct * 16 + l15) ^ ((prow & 7) << 3))] = f2bf(e);
          }
        }
      }
      // Wave-local P round-trip (rows [wave*32, wave*32+32) exclusive to wave).
#pragma unroll
      for (int s = 0; s < 2; s++) {
        const int prow = wave * 32 + s * 16 + l15;
        const int psw = (l15 & 7) << 3;
#pragma unroll
        for (int ks = 0; ks < 2; ks++)
          pf[s][c][ks] = *(const short8*)(&Ps[prow * 64 + ((ks * 32 + l4 * 8) ^ psw)]);
      }
    }

    // ---- PV + row sums
    __builtin_amdgcn_s_setprio(1);
#pragma unroll
    for (int nt = 0; nt < 8; nt++) {
      const int vrow = nt * 16 + l15;
      const int vsw = (vrow & 7) << 3;
      const short8 v0 = *(const short8*)(&Vs[vrow * 64 + ((l4 * 8) ^ vsw)]);
      const short8 v1 = *(const short8*)(&Vs[vrow * 64 + ((32 + l4 * 8) ^ vsw)]);
#pragma unroll
      for (int s = 0; s < 2; s++) {
        accO[s][0][nt] = __builtin_amdgcn_mfma_f32_16x16x32_bf16(pf[s][0][0], v0, accO[s][0][nt], 0, 0, 0);
        accO[s][0][nt] = __builtin_amdgcn_mfma_f32_16x16x32_bf16(pf[s][0][1], v1, accO[s][0][nt], 0, 0, 0);
        accO[s][1][nt] = __builtin_amdgcn_mfma_f32_16x16x32_bf16(pf[s][1][0], v0, accO[s][1][nt], 0, 0, 0);
        accO[s][1][nt] = __builtin_amdgcn_mfma_f32_16x16x32_bf16(pf[s][1][1], v1, accO[s][1][nt], 0, 0, 0);
      }
    }
#pragma unroll
    for (int s = 0; s < 2; s++)
#pragma unroll
      for (int c = 0; c < 2; c++) {
        accL[s][c] = __builtin_amdgcn_mfma_f32_16x16x32_bf16(pf[s][c][0], onesf, accL[s][c], 0, 0, 0);
        accL[s][c] = __builtin_amdgcn_mfma_f32_16x16x32_bf16(pf[s][c][1], onesf, accL[s][c], 0, 0, 0);
      }
    __builtin_amdgcn_s_setprio(0);
  }

  // Epilogue: o1 - lam*o2, RMS-norm over 128, * subln_w * (1 - lambda_init).
  float wv[8];
#pragma unroll
  for (int nt = 0; nt < 8; nt++) wv[nt] = wsub[nt * 16 + l15];
#pragma unroll
  for (int s = 0; s < 2; s++)
#pragma unroll
    for (int r = 0; r < 4; r++) {
      const float l1 = __shfl(accL[s][0][r], lane & 48);
      const float l2 = __shfl(accL[s][1][r], lane & 48);
      const float i1 = 1.f / fmaxf(l1, 1e-30f);
      const float i2 = lam / fmaxf(l2, 1e-30f);
      float av[8], ss = 0.f;
#pragma unroll
      for (int nt = 0; nt < 8; nt++) {
        const float a = accO[s][0][nt][r] * i1 - accO[s][1][nt][r] * i2;
        av[nt] = a;
        ss += a * a;
      }
#pragma unroll
      for (int off = 1; off < 16; off <<= 1) ss += __shfl_xor(ss, off, 16);
      const float sca = rsqrtf(ss * (1.f / 128.f) + 1e-5f) * (1.f - LAMBDA_INIT);
      const int qrow = q0 + wave * 32 + s * 16 + l4 * 4 + r;
      unsigned short* Ao = Ab + ((size_t)(b * 2048 + qrow)) * 2048 + h * 128;
#pragma unroll
      for (int nt = 0; nt < 8; nt++)
        Ao[nt * 16 + l15] = f2bf(av[nt] * sca * wv[nt]);
    }
}

extern "C" void kernel_launch(void* const* d_in, const int* in_sizes, int n_in,
                              void* d_out, int out_size, void* d_ws, size_t ws_size,
                              hipStream_t stream) {
  const float* x    = (const float*)d_in[0];
  const float* cosb = (const float*)d_in[1];
  const float* sinb = (const float*)d_in[2];
  const float* Wq   = (const float*)d_in[3];
  const float* Wk   = (const float*)d_in[4];
  const float* Wv   = (const float*)d_in[5];
  const float* Wo   = (const float*)d_in[6];
  const float* lq1  = (const float*)d_in[7];
  const float* lk1  = (const float*)d_in[8];
  const float* lq2  = (const float*)d_in[9];
  const float* lk2  = (const float*)d_in[10];
  const float* wsub = (const float*)d_in[11];
  float* out = (float*)d_out;

  // ws layout (fast, ws>=40MiB): [0,16) xb -> later A | [16,24) Wqb | [24,28) Wkb
  //   | [28,32) Wvb | [32,40) Wob.  Fallback (ws>=16MiB): [0,16) xb -> A.
  // d_out (32 MiB f32) temporarily hosts bf16 K(8) | Vt(8) | Q(16); O-GEMM
  // overwrites d_out with f32 C (K/Vt/Q dead by then).
  unsigned short* XA  = (unsigned short*)d_ws;
  unsigned short* Kb  = (unsigned short*)d_out;
  unsigned short* Vtb = Kb + (size_t)4096 * 1024;
  unsigned short* Qb  = Vtb + (size_t)2 * 1024 * 2048;

  dim3 blk(256);
  if (ws_size >= (size_t)41943040) {
    unsigned short* Wqb = XA + 8388608;
    unsigned short* Wkb = XA + 12582912;
    unsigned short* Wvb = XA + 14680064;
    unsigned short* Wob = XA + 16777216;
    conv_all<<<10240, blk, 0, stream>>>(x, Wq, Wk, Wv, Wo, XA);
    qkv_bb<<<dim3(32, 32), blk, 0, stream>>>(XA, Wqb, Wkb, Wvb, cosb, sinb, Qb, Kb, Vtb);
    attn_kernel<<<dim3(16, 32), blk, 0, stream>>>(Qb, Kb, Vtb, XA, lq1, lk1, lq2, lk2, wsub);
    o_bb<<<dim3(16, 32), blk, 0, stream>>>(XA, Wob, out);
  } else {
    conv_bf16<<<4096, blk, 0, stream>>>(x, XA, 1048576);
    qkv_gemm_f32<<<dim3(32, 32), blk, 0, stream>>>(XA, Wq, Wk, Wv, cosb, sinb, Qb, Kb, Vtb);
    attn_kernel<<<dim3(16, 32), blk, 0, stream>>>(Qb, Kb, Vtb, XA, lq1, lk1, lq2, lk2, wsub);
    o_gemm_f32<<<dim3(16, 32), blk, 0, stream>>>(XA, Wo, out);
  }
}